// Round 1
// baseline (1946.658 us; speedup 1.0000x reference)
//
#include <hip/hip_runtime.h>
#include <math.h>

#define B_ 4
#define L_ 4096
#define D_ 1024
#define A_ 64
#define FF_ 2048
#define N_ (B_*L_)
#define EPS_ 1e-6f
#define CHUNK_ 128
#define NCHUNK_ (L_/CHUNK_)

static __device__ __forceinline__ float sigmoidf_(float x) { return 1.f/(1.f+expf(-x)); }
static __device__ __forceinline__ float siluf_(float x)    { return x/(1.f+expf(-x)); }

// ---------------- rms (one wave per row): rms[row] = rsqrt(mean(x^2)+eps) ----------------
__global__ __launch_bounds__(256) void rms_kernel(const float* __restrict__ x,
                                                  float* __restrict__ rms)
{
    int row  = blockIdx.x*4 + (threadIdx.x>>6);
    int lane = threadIdx.x & 63;
    const float4* xr = (const float4*)(x + (size_t)row*D_);
    float s = 0.f;
#pragma unroll
    for (int j = 0; j < 4; j++) {
        float4 v = xr[lane + 64*j];
        s += v.x*v.x + v.y*v.y + v.z*v.z + v.w*v.w;
    }
#pragma unroll
    for (int off = 32; off > 0; off >>= 1) s += __shfl_xor(s, off);
    if (lane == 0) rms[row] = rsqrtf(s*(1.f/(float)D_) + EPS_);
}

// ---------------- SSM scan phase 1: per-chunk partial (h_local at chunk end) ----------------
__global__ __launch_bounds__(64) void scan1_kernel(
    const float* __restrict__ x, const float* __restrict__ rms1,
    const float* __restrict__ n1w, const float* __restrict__ bw,
    const float* __restrict__ araw, float* __restrict__ cpart)
{
    int d = blockIdx.x*64 + threadIdx.x;
    int c = blockIdx.y;
    int b = blockIdx.z;
    float a = sigmoidf_(araw[d]);
    float w = n1w[d]*bw[d];
    float h = 0.f;
    size_t base = ((size_t)b*L_ + (size_t)c*CHUNK_)*D_ + d;
    const float* rp = rms1 + b*L_ + c*CHUNK_;
#pragma unroll 8
    for (int t = 0; t < CHUNK_; t++) {
        float u = x[base + (size_t)t*D_] * rp[t] * w;
        h = a*h + u;
    }
    cpart[((size_t)b*NCHUNK_ + c)*D_ + d] = h;
}

// ---------------- SSM scan phase 2: prefix over chunk carries ----------------
__global__ __launch_bounds__(256) void scan2_kernel(
    const float* __restrict__ araw, const float* __restrict__ cpart,
    float* __restrict__ cin)
{
    int idx = blockIdx.x*256 + threadIdx.x;   // over B*D
    int b = idx >> 10;
    int d = idx & (D_-1);
    float a = sigmoidf_(araw[d]);
    float aT = a;
#pragma unroll
    for (int i = 0; i < 7; i++) aT *= aT;     // a^128
    float cy = 0.f;
    for (int c = 0; c < NCHUNK_; c++) {
        size_t o = ((size_t)b*NCHUNK_ + c)*D_ + d;
        cin[o] = cy;
        cy = aT*cy + cpart[o];
    }
}

// ---------------- SSM scan phase 3: recompute with carry, write x_ssm = x + h*c_w ----------------
__global__ __launch_bounds__(64) void scan3_kernel(
    const float* __restrict__ x, const float* __restrict__ rms1,
    const float* __restrict__ n1w, const float* __restrict__ bw,
    const float* __restrict__ cw, const float* __restrict__ araw,
    const float* __restrict__ cin, float* __restrict__ x_ssm)
{
    int d = blockIdx.x*64 + threadIdx.x;
    int c = blockIdx.y;
    int b = blockIdx.z;
    float a = sigmoidf_(araw[d]);
    float w = n1w[d]*bw[d];
    float cwd = cw[d];
    float h = cin[((size_t)b*NCHUNK_ + c)*D_ + d];
    size_t base = ((size_t)b*L_ + (size_t)c*CHUNK_)*D_ + d;
    const float* rp = rms1 + b*L_ + c*CHUNK_;
#pragma unroll 8
    for (int t = 0; t < CHUNK_; t++) {
        size_t p = base + (size_t)t*D_;
        float xv = x[p];
        h = a*h + xv * rp[t] * w;
        x_ssm[p] = xv + h*cwd;
    }
}

// ---------------- QKV projection: C[M,64] = x_ssm[M,1024] @ W[1024,64] ----------------
__global__ __launch_bounds__(256) void gemm_qkv(
    const float* __restrict__ xs,
    const float* __restrict__ Wq, const float* __restrict__ Wk,
    const float* __restrict__ Wv,
    float* __restrict__ qo, float* __restrict__ ko, float* __restrict__ vo)
{
    __shared__ float As[32][128];
    __shared__ float Bs[32][64];
    const float* Bmat = (blockIdx.y == 0) ? Wq : (blockIdx.y == 1) ? Wk : Wv;
    float* C          = (blockIdx.y == 0) ? qo : (blockIdx.y == 1) ? ko : vo;
    const int t   = threadIdx.x;
    const int m0  = blockIdx.x*128;
    const int c_t = t & 15;
    const int r_t = t >> 4;
    const int arow = t >> 3;
    const int af4  = t & 7;
    float acc[8][4] = {};

    for (int k0 = 0; k0 < D_; k0 += 32) {
#pragma unroll
        for (int i = 0; i < 4; i++) {
            int row = i*32 + arow;
            float4 v = *(const float4*)(xs + (size_t)(m0+row)*D_ + k0 + af4*4);
            As[af4*4+0][row] = v.x;
            As[af4*4+1][row] = v.y;
            As[af4*4+2][row] = v.z;
            As[af4*4+3][row] = v.w;
        }
#pragma unroll
        for (int i = 0; i < 2; i++) {
            int lin = i*256 + t;
            int row = lin >> 4;
            int f4  = lin & 15;
            *(float4*)&Bs[row][f4*4] =
                *(const float4*)(Bmat + (size_t)(k0+row)*A_ + f4*4);
        }
        __syncthreads();
#pragma unroll
        for (int kk = 0; kk < 32; kk++) {
            float Af[8], Bf[4];
            *(float4*)&Af[0] = *(const float4*)&As[kk][r_t*4];
            *(float4*)&Af[4] = *(const float4*)&As[kk][r_t*4 + 64];
            *(float4*)&Bf[0] = *(const float4*)&Bs[kk][c_t*4];
#pragma unroll
            for (int i = 0; i < 8; i++)
#pragma unroll
                for (int j = 0; j < 4; j++)
                    acc[i][j] = fmaf(Af[i], Bf[j], acc[i][j]);
        }
        __syncthreads();
    }
#pragma unroll
    for (int i = 0; i < 8; i++) {
        int row = m0 + (i>>2)*64 + r_t*4 + (i&3);
        float4 o;
        o.x = acc[i][0]; o.y = acc[i][1]; o.z = acc[i][2]; o.w = acc[i][3];
        *(float4*)(C + (size_t)row*A_ + c_t*4) = o;
    }
}

// ---------------- gate = sigmoid(x_ssm @ Wg + bias), one wave per row ----------------
__global__ __launch_bounds__(256) void gate_kernel(
    const float* __restrict__ xs, const float* __restrict__ Wg,
    const float* __restrict__ gb, float* __restrict__ gate)
{
    int row  = blockIdx.x*4 + (threadIdx.x>>6);
    int lane = threadIdx.x & 63;
    const float4* xr = (const float4*)(xs + (size_t)row*D_);
    const float4* wr = (const float4*)Wg;
    float s = 0.f;
#pragma unroll
    for (int j = 0; j < 4; j++) {
        float4 xv = xr[lane + 64*j];
        float4 wv = wr[lane + 64*j];
        s += xv.x*wv.x + xv.y*wv.y + xv.z*wv.z + xv.w*wv.w;
    }
#pragma unroll
    for (int off = 32; off > 0; off >>= 1) s += __shfl_xor(s, off);
    if (lane == 0) gate[row] = sigmoidf_(s + gb[0]);
}

// ---------------- sliding-window attention (W=64, hd=64), 64 queries / block ----------------
__global__ __launch_bounds__(256) void attn_kernel(
    const float* __restrict__ qm, const float* __restrict__ km,
    const float* __restrict__ vm, float* __restrict__ om)
{
    __shared__ float KV[128][68];    // stride 68 floats: even bank spread for b128 reads
    int b  = blockIdx.y;
    int l0 = blockIdx.x*64;
    int t  = threadIdx.x;
    int r  = t >> 2;                 // query row within tile (0..63)
    int qq = t & 3;                  // quarter (16 window slots / 16 out dims)

    // stage K rows l0-64 .. l0+63
#pragma unroll
    for (int i = 0; i < 8; i++) {
        int lin = i*256 + t;
        int row = lin >> 4;
        int f4  = lin & 15;
        int gl  = l0 - 64 + row;
        float4 val = make_float4(0.f,0.f,0.f,0.f);
        if (gl >= 0) val = *(const float4*)(km + ((size_t)b*L_ + gl)*A_ + f4*4);
        *(float4*)&KV[row][f4*4] = val;
    }
    float4 qreg[16];
    {
        const float* qrow = qm + ((size_t)b*L_ + l0 + r)*A_;
#pragma unroll
        for (int j = 0; j < 16; j++) qreg[j] = *(const float4*)(qrow + j*4);
    }
    __syncthreads();

    float s[16];
#pragma unroll
    for (int wi = 0; wi < 16; wi++) {
        int w  = qq*16 + wi;
        int tr = r + w + 1;          // tile row of global l0+r-63+w (tile row0 = l0-64)
        float dot = 0.f;
#pragma unroll
        for (int j = 0; j < 16; j++) {
            float4 kv = *(const float4*)&KV[tr][j*4];
            dot += qreg[j].x*kv.x + qreg[j].y*kv.y + qreg[j].z*kv.z + qreg[j].w*kv.w;
        }
        s[wi] = (l0 + r - 63 + w >= 0) ? dot*0.125f : -INFINITY;
    }
    // softmax across 4-lane group (group = lanes of same r)
    float mx = s[0];
#pragma unroll
    for (int wi = 1; wi < 16; wi++) mx = fmaxf(mx, s[wi]);
    mx = fmaxf(mx, __shfl_xor(mx, 1));
    mx = fmaxf(mx, __shfl_xor(mx, 2));
    float sum = 0.f;
#pragma unroll
    for (int wi = 0; wi < 16; wi++) { s[wi] = expf(s[wi] - mx); sum += s[wi]; }
    sum += __shfl_xor(sum, 1);
    sum += __shfl_xor(sum, 2);
    float inv = 1.f/sum;
#pragma unroll
    for (int wi = 0; wi < 16; wi++) s[wi] *= inv;

    __syncthreads();                 // all done reading K
    // stage V into the same buffer
#pragma unroll
    for (int i = 0; i < 8; i++) {
        int lin = i*256 + t;
        int row = lin >> 4;
        int f4  = lin & 15;
        int gl  = l0 - 64 + row;
        float4 val = make_float4(0.f,0.f,0.f,0.f);
        if (gl >= 0) val = *(const float4*)(vm + ((size_t)b*L_ + gl)*A_ + f4*4);
        *(float4*)&KV[row][f4*4] = val;
    }
    __syncthreads();

    float4 acc[4];
#pragma unroll
    for (int ss = 0; ss < 4; ss++) acc[ss] = make_float4(0.f,0.f,0.f,0.f);
#pragma unroll
    for (int w = 0; w < 64; w++) {
        float pv = __shfl(s[w & 15], (t & 60) + (w >> 4));   // p[w] of this row
        int tr = r + w + 1;
#pragma unroll
        for (int ss = 0; ss < 4; ss++) {
            float4 vv = *(const float4*)&KV[tr][qq*16 + ss*4];
            acc[ss].x += pv*vv.x; acc[ss].y += pv*vv.y;
            acc[ss].z += pv*vv.z; acc[ss].w += pv*vv.w;
        }
    }
    float* orow = om + ((size_t)b*L_ + l0 + r)*A_ + qq*16;
#pragma unroll
    for (int ss = 0; ss < 4; ss++) *(float4*)(orow + ss*4) = acc[ss];
}

// ---------------- 128x128 f32 GEMM, MODE: 0=FF1(rms-scale A, silu out) 1=FF2(+resid) 2=WO(resid+gate*acc) ----------------
template<int MODE>
__global__ __launch_bounds__(256) void gemm128(
    const float* __restrict__ Amat, int lda, int K,
    const float* __restrict__ Bmat, int ldb,
    float* Cmat, int ldc,
    const float* __restrict__ rowscale,   // FF1: rms2, WO: gate
    const float* __restrict__ colscale,   // FF1: norm2_w (indexed by k)
    const float* resid)                   // FF2 / WO residual (may alias Cmat in FF2)
{
    __shared__ float As[32][128];   // As[k][m]
    __shared__ float Bs[32][128];   // Bs[k][n]
    const int t   = threadIdx.x;
    const int m0  = blockIdx.x*128;
    const int n0  = blockIdx.y*128;
    const int c_t = t & 15;
    const int r_t = t >> 4;
    const int arow = t >> 3;
    const int af4  = t & 7;
    const int brow = t >> 5;
    const int bf4  = t & 31;
    float acc[8][8] = {};

    for (int k0 = 0; k0 < K; k0 += 32) {
#pragma unroll
        for (int i = 0; i < 4; i++) {
            int row = i*32 + arow;
            float4 v = *(const float4*)(Amat + (size_t)(m0+row)*lda + k0 + af4*4);
            if (MODE == 0) {
                float rs = rowscale[m0+row];
                float4 cs = *(const float4*)(colscale + k0 + af4*4);
                v.x *= rs*cs.x; v.y *= rs*cs.y; v.z *= rs*cs.z; v.w *= rs*cs.w;
            }
            As[af4*4+0][row] = v.x;
            As[af4*4+1][row] = v.y;
            As[af4*4+2][row] = v.z;
            As[af4*4+3][row] = v.w;
        }
#pragma unroll
        for (int i = 0; i < 4; i++) {
            int row = i*8 + brow;
            *(float4*)&Bs[row][bf4*4] =
                *(const float4*)(Bmat + (size_t)(k0+row)*ldb + n0 + bf4*4);
        }
        __syncthreads();
#pragma unroll
        for (int kk = 0; kk < 32; kk++) {
            float Af[8], Bf[8];
            *(float4*)&Af[0] = *(const float4*)&As[kk][r_t*4];
            *(float4*)&Af[4] = *(const float4*)&As[kk][r_t*4 + 64];
            *(float4*)&Bf[0] = *(const float4*)&Bs[kk][c_t*4];
            *(float4*)&Bf[4] = *(const float4*)&Bs[kk][c_t*4 + 64];
#pragma unroll
            for (int i = 0; i < 8; i++)
#pragma unroll
                for (int j = 0; j < 8; j++)
                    acc[i][j] = fmaf(Af[i], Bf[j], acc[i][j]);
        }
        __syncthreads();
    }
#pragma unroll
    for (int i = 0; i < 8; i++) {
        int row = m0 + (i>>2)*64 + r_t*4 + (i&3);
#pragma unroll
        for (int jg = 0; jg < 2; jg++) {
            int col = n0 + jg*64 + c_t*4;
            float4 o;
            o.x = acc[i][jg*4+0]; o.y = acc[i][jg*4+1];
            o.z = acc[i][jg*4+2]; o.w = acc[i][jg*4+3];
            if (MODE == 0) {
                o.x = siluf_(o.x); o.y = siluf_(o.y);
                o.z = siluf_(o.z); o.w = siluf_(o.w);
            } else if (MODE == 1) {
                float4 rr = *(const float4*)(resid + (size_t)row*ldc + col);
                o.x += rr.x; o.y += rr.y; o.z += rr.z; o.w += rr.w;
            } else {
                float g = rowscale[row];
                float4 rr = *(const float4*)(resid + (size_t)row*ldc + col);
                o.x = rr.x + g*o.x; o.y = rr.y + g*o.y;
                o.z = rr.z + g*o.z; o.w = rr.w + g*o.w;
            }
            *(float4*)(Cmat + (size_t)row*ldc + col) = o;
        }
    }
}

extern "C" void kernel_launch(void* const* d_in, const int* in_sizes, int n_in,
                              void* d_out, int out_size, void* d_ws, size_t ws_size,
                              hipStream_t stream)
{
    const float* x    = (const float*)d_in[0];
    const float* n1w  = (const float*)d_in[1];
    const float* n2w  = (const float*)d_in[2];
    const float* araw = (const float*)d_in[3];
    const float* bw   = (const float*)d_in[4];
    const float* cw   = (const float*)d_in[5];
    const float* Wq   = (const float*)d_in[6];
    const float* Wk   = (const float*)d_in[7];
    const float* Wv   = (const float*)d_in[8];
    const float* Wo   = (const float*)d_in[9];
    const float* Wg   = (const float*)d_in[10];
    const float* gb   = (const float*)d_in[11];
    const float* ffw1 = (const float*)d_in[12];
    const float* ffw2 = (const float*)d_in[13];
    float* out = (float*)d_out;

    float* ws    = (float*)d_ws;
    float* rms1  = ws;                                   // N_
    float* rms2  = rms1  + N_;                           // N_
    float* gate  = rms2  + N_;                           // N_
    float* cpart = gate  + N_;                           // B_*NCHUNK_*D_
    float* cin   = cpart + (size_t)B_*NCHUNK_*D_;        // B_*NCHUNK_*D_
    float* qb    = cin   + (size_t)B_*NCHUNK_*D_;        // N_*A_
    float* kb    = qb    + (size_t)N_*A_;
    float* vb    = kb    + (size_t)N_*A_;
    float* attnb = vb    + (size_t)N_*A_;
    float* x_ssm = attnb + (size_t)N_*A_;                // N_*D_
    float* act   = x_ssm + (size_t)N_*D_;                // N_*FF_

    // 1. rms of x
    rms_kernel<<<N_/4, 256, 0, stream>>>(x, rms1);
    // 2-4. chunked SSM scan -> x_ssm = x + h*c_w
    scan1_kernel<<<dim3(D_/64, NCHUNK_, B_), 64, 0, stream>>>(x, rms1, n1w, bw, araw, cpart);
    scan2_kernel<<<(B_*D_)/256, 256, 0, stream>>>(araw, cpart, cin);
    scan3_kernel<<<dim3(D_/64, NCHUNK_, B_), 64, 0, stream>>>(x, rms1, n1w, bw, cw, araw, cin, x_ssm);
    // 5. q,k,v projections
    gemm_qkv<<<dim3(N_/128, 3), 256, 0, stream>>>(x_ssm, Wq, Wk, Wv, qb, kb, vb);
    // 6. gate
    gate_kernel<<<N_/4, 256, 0, stream>>>(x_ssm, Wg, gb, gate);
    // 7. sliding-window attention
    attn_kernel<<<dim3(L_/64, B_), 256, 0, stream>>>(qb, kb, vb, attnb);
    // 8. x_att = x_ssm + gate * (attn @ Wo)   (into d_out, reused as scratch)
    gemm128<2><<<dim3(N_/128, D_/128), 256, 0, stream>>>(attnb, A_, A_, Wo, D_, out, D_,
                                                         gate, (const float*)0, x_ssm);
    // 9. rms of x_att
    rms_kernel<<<N_/4, 256, 0, stream>>>(out, rms2);
    // 10. act = silu((x_att*rms2*n2w) @ ff_w1)
    gemm128<0><<<dim3(N_/128, FF_/128), 256, 0, stream>>>(out, D_, D_, ffw1, FF_, act, FF_,
                                                          rms2, n2w, (const float*)0);
    // 11. y = x_att + act @ ff_w2  (in-place on d_out)
    gemm128<1><<<dim3(N_/128, D_/128), 256, 0, stream>>>(act, FF_, FF_, ffw2, D_, out, D_,
                                                         (const float*)0, (const float*)0, out);
}

// Round 2
// 647.508 us; speedup vs baseline: 3.0064x; 3.0064x over previous
//
#include <hip/hip_runtime.h>
#include <math.h>

#define B_ 4
#define L_ 4096
#define D_ 1024
#define A_ 64
#define FF_ 2048
#define N_ (B_*L_)
#define EPS_ 1e-6f
#define CHUNK_ 128
#define NCHUNK_ (L_/CHUNK_)

typedef __attribute__((ext_vector_type(8))) short bf16x8;
typedef __attribute__((ext_vector_type(4))) short s16x4;
typedef __attribute__((ext_vector_type(4))) float f32x4;

static __device__ __forceinline__ float sigmoidf_(float x) { return 1.f/(1.f+expf(-x)); }
static __device__ __forceinline__ float siluf_(float x)    { return x/(1.f+expf(-x)); }

static __device__ __forceinline__ unsigned short f2bf(float f) {
    unsigned u = __float_as_uint(f);
    u += 0x7fffu + ((u >> 16) & 1u);        // RNE
    return (unsigned short)(u >> 16);
}

// async global->LDS, 16B per lane; lds ptr must be wave-uniform (HW adds lane*16)
static __device__ __forceinline__ void gload16(const short* g, short* l) {
    __builtin_amdgcn_global_load_lds(
        (const __attribute__((address_space(1))) void*)g,
        (__attribute__((address_space(3))) void*)l, 16, 0, 0);
}

// ---------------- rms (one wave per row): rms[row] = rsqrt(mean(x^2)+eps) ----------------
__global__ __launch_bounds__(256) void rms_kernel(const float* __restrict__ x,
                                                  float* __restrict__ rms)
{
    int row  = blockIdx.x*4 + (threadIdx.x>>6);
    int lane = threadIdx.x & 63;
    const float4* xr = (const float4*)(x + (size_t)row*D_);
    float s = 0.f;
#pragma unroll
    for (int j = 0; j < 4; j++) {
        float4 v = xr[lane + 64*j];
        s += v.x*v.x + v.y*v.y + v.z*v.z + v.w*v.w;
    }
#pragma unroll
    for (int off = 32; off > 0; off >>= 1) s += __shfl_xor(s, off);
    if (lane == 0) rms[row] = rsqrtf(s*(1.f/(float)D_) + EPS_);
}

// ---------------- SSM scan phase 1 ----------------
__global__ __launch_bounds__(64) void scan1_kernel(
    const float* __restrict__ x, const float* __restrict__ rms1,
    const float* __restrict__ n1w, const float* __restrict__ bw,
    const float* __restrict__ araw, float* __restrict__ cpart)
{
    int d = blockIdx.x*64 + threadIdx.x;
    int c = blockIdx.y;
    int b = blockIdx.z;
    float a = sigmoidf_(araw[d]);
    float w = n1w[d]*bw[d];
    float h = 0.f;
    size_t base = ((size_t)b*L_ + (size_t)c*CHUNK_)*D_ + d;
    const float* rp = rms1 + b*L_ + c*CHUNK_;
#pragma unroll 8
    for (int t = 0; t < CHUNK_; t++) {
        float u = x[base + (size_t)t*D_] * rp[t] * w;
        h = a*h + u;
    }
    cpart[((size_t)b*NCHUNK_ + c)*D_ + d] = h;
}

// ---------------- SSM scan phase 2 ----------------
__global__ __launch_bounds__(256) void scan2_kernel(
    const float* __restrict__ araw, const float* __restrict__ cpart,
    float* __restrict__ cin)
{
    int idx = blockIdx.x*256 + threadIdx.x;   // over B*D
    int b = idx >> 10;
    int d = idx & (D_-1);
    float a = sigmoidf_(araw[d]);
    float aT = a;
#pragma unroll
    for (int i = 0; i < 7; i++) aT *= aT;     // a^128
    float cy = 0.f;
    for (int c = 0; c < NCHUNK_; c++) {
        size_t o = ((size_t)b*NCHUNK_ + c)*D_ + d;
        cin[o] = cy;
        cy = aT*cy + cpart[o];
    }
}

// ---------------- SSM scan phase 3 ----------------
__global__ __launch_bounds__(64) void scan3_kernel(
    const float* __restrict__ x, const float* __restrict__ rms1,
    const float* __restrict__ n1w, const float* __restrict__ bw,
    const float* __restrict__ cw, const float* __restrict__ araw,
    const float* __restrict__ cin, float* __restrict__ x_ssm)
{
    int d = blockIdx.x*64 + threadIdx.x;
    int c = blockIdx.y;
    int b = blockIdx.z;
    float a = sigmoidf_(araw[d]);
    float w = n1w[d]*bw[d];
    float cwd = cw[d];
    float h = cin[((size_t)b*NCHUNK_ + c)*D_ + d];
    size_t base = ((size_t)b*L_ + (size_t)c*CHUNK_)*D_ + d;
    const float* rp = rms1 + b*L_ + c*CHUNK_;
#pragma unroll 8
    for (int t = 0; t < CHUNK_; t++) {
        size_t p = base + (size_t)t*D_;
        float xv = x[p];
        h = a*h + xv * rp[t] * w;
        x_ssm[p] = xv + h*cwd;
    }
}

// ---------------- QKV projection (f32) ----------------
__global__ __launch_bounds__(256) void gemm_qkv(
    const float* __restrict__ xs,
    const float* __restrict__ Wq, const float* __restrict__ Wk,
    const float* __restrict__ Wv,
    float* __restrict__ qo, float* __restrict__ ko, float* __restrict__ vo)
{
    __shared__ float As[32][128];
    __shared__ float Bs[32][64];
    const float* Bmat = (blockIdx.y == 0) ? Wq : (blockIdx.y == 1) ? Wk : Wv;
    float* C          = (blockIdx.y == 0) ? qo : (blockIdx.y == 1) ? ko : vo;
    const int t   = threadIdx.x;
    const int m0  = blockIdx.x*128;
    const int c_t = t & 15;
    const int r_t = t >> 4;
    const int arow = t >> 3;
    const int af4  = t & 7;
    float acc[8][4] = {};

    for (int k0 = 0; k0 < D_; k0 += 32) {
#pragma unroll
        for (int i = 0; i < 4; i++) {
            int row = i*32 + arow;
            float4 v = *(const float4*)(xs + (size_t)(m0+row)*D_ + k0 + af4*4);
            As[af4*4+0][row] = v.x;
            As[af4*4+1][row] = v.y;
            As[af4*4+2][row] = v.z;
            As[af4*4+3][row] = v.w;
        }
#pragma unroll
        for (int i = 0; i < 2; i++) {
            int lin = i*256 + t;
            int row = lin >> 4;
            int f4  = lin & 15;
            *(float4*)&Bs[row][f4*4] =
                *(const float4*)(Bmat + (size_t)(k0+row)*A_ + f4*4);
        }
        __syncthreads();
#pragma unroll
        for (int kk = 0; kk < 32; kk++) {
            float Af[8], Bf[4];
            *(float4*)&Af[0] = *(const float4*)&As[kk][r_t*4];
            *(float4*)&Af[4] = *(const float4*)&As[kk][r_t*4 + 64];
            *(float4*)&Bf[0] = *(const float4*)&Bs[kk][c_t*4];
#pragma unroll
            for (int i = 0; i < 8; i++)
#pragma unroll
                for (int j = 0; j < 4; j++)
                    acc[i][j] = fmaf(Af[i], Bf[j], acc[i][j]);
        }
        __syncthreads();
    }
#pragma unroll
    for (int i = 0; i < 8; i++) {
        int row = m0 + (i>>2)*64 + r_t*4 + (i&3);
        float4 o;
        o.x = acc[i][0]; o.y = acc[i][1]; o.z = acc[i][2]; o.w = acc[i][3];
        *(float4*)(C + (size_t)row*A_ + c_t*4) = o;
    }
}

// ---------------- gate ----------------
__global__ __launch_bounds__(256) void gate_kernel(
    const float* __restrict__ xs, const float* __restrict__ Wg,
    const float* __restrict__ gb, float* __restrict__ gate)
{
    int row  = blockIdx.x*4 + (threadIdx.x>>6);
    int lane = threadIdx.x & 63;
    const float4* xr = (const float4*)(xs + (size_t)row*D_);
    const float4* wr = (const float4*)Wg;
    float s = 0.f;
#pragma unroll
    for (int j = 0; j < 4; j++) {
        float4 xv = xr[lane + 64*j];
        float4 wv = wr[lane + 64*j];
        s += xv.x*wv.x + xv.y*wv.y + xv.z*wv.z + xv.w*wv.w;
    }
#pragma unroll
    for (int off = 32; off > 0; off >>= 1) s += __shfl_xor(s, off);
    if (lane == 0) gate[row] = sigmoidf_(s + gb[0]);
}

// ---------------- sliding-window attention (f32) ----------------
__global__ __launch_bounds__(256) void attn_kernel(
    const float* __restrict__ qm, const float* __restrict__ km,
    const float* __restrict__ vm, float* __restrict__ om)
{
    __shared__ float KV[128][68];
    int b  = blockIdx.y;
    int l0 = blockIdx.x*64;
    int t  = threadIdx.x;
    int r  = t >> 2;
    int qq = t & 3;

#pragma unroll
    for (int i = 0; i < 8; i++) {
        int lin = i*256 + t;
        int row = lin >> 4;
        int f4  = lin & 15;
        int gl  = l0 - 64 + row;
        float4 val = make_float4(0.f,0.f,0.f,0.f);
        if (gl >= 0) val = *(const float4*)(km + ((size_t)b*L_ + gl)*A_ + f4*4);
        *(float4*)&KV[row][f4*4] = val;
    }
    float4 qreg[16];
    {
        const float* qrow = qm + ((size_t)b*L_ + l0 + r)*A_;
#pragma unroll
        for (int j = 0; j < 16; j++) qreg[j] = *(const float4*)(qrow + j*4);
    }
    __syncthreads();

    float s[16];
#pragma unroll
    for (int wi = 0; wi < 16; wi++) {
        int w  = qq*16 + wi;
        int tr = r + w + 1;
        float dot = 0.f;
#pragma unroll
        for (int j = 0; j < 16; j++) {
            float4 kv = *(const float4*)&KV[tr][j*4];
            dot += qreg[j].x*kv.x + qreg[j].y*kv.y + qreg[j].z*kv.z + qreg[j].w*kv.w;
        }
        s[wi] = (l0 + r - 63 + w >= 0) ? dot*0.125f : -INFINITY;
    }
    float mx = s[0];
#pragma unroll
    for (int wi = 1; wi < 16; wi++) mx = fmaxf(mx, s[wi]);
    mx = fmaxf(mx, __shfl_xor(mx, 1));
    mx = fmaxf(mx, __shfl_xor(mx, 2));
    float sum = 0.f;
#pragma unroll
    for (int wi = 0; wi < 16; wi++) { s[wi] = expf(s[wi] - mx); sum += s[wi]; }
    sum += __shfl_xor(sum, 1);
    sum += __shfl_xor(sum, 2);
    float inv = 1.f/sum;
#pragma unroll
    for (int wi = 0; wi < 16; wi++) s[wi] *= inv;

    __syncthreads();
#pragma unroll
    for (int i = 0; i < 8; i++) {
        int lin = i*256 + t;
        int row = lin >> 4;
        int f4  = lin & 15;
        int gl  = l0 - 64 + row;
        float4 val = make_float4(0.f,0.f,0.f,0.f);
        if (gl >= 0) val = *(const float4*)(vm + ((size_t)b*L_ + gl)*A_ + f4*4);
        *(float4*)&KV[row][f4*4] = val;
    }
    __syncthreads();

    float4 acc[4];
#pragma unroll
    for (int ss = 0; ss < 4; ss++) acc[ss] = make_float4(0.f,0.f,0.f,0.f);
#pragma unroll
    for (int w = 0; w < 64; w++) {
        float pv = __shfl(s[w & 15], (t & 60) + (w >> 4));
        int tr = r + w + 1;
#pragma unroll
        for (int ss = 0; ss < 4; ss++) {
            float4 vv = *(const float4*)&KV[tr][qq*16 + ss*4];
            acc[ss].x += pv*vv.x; acc[ss].y += pv*vv.y;
            acc[ss].z += pv*vv.z; acc[ss].w += pv*vv.w;
        }
    }
    float* orow = om + ((size_t)b*L_ + l0 + r)*A_ + qq*16;
#pragma unroll
    for (int ss = 0; ss < 4; ss++) *(float4*)(orow + ss*4) = acc[ss];
}

// ---------------- f32 GEMM for WO: C = resid + gate*(A@B) ----------------
template<int MODE>
__global__ __launch_bounds__(256) void gemm128(
    const float* __restrict__ Amat, int lda, int K,
    const float* __restrict__ Bmat, int ldb,
    float* Cmat, int ldc,
    const float* __restrict__ rowscale,
    const float* __restrict__ colscale,
    const float* resid)
{
    __shared__ float As[32][128];
    __shared__ float Bs[32][128];
    const int t   = threadIdx.x;
    const int m0  = blockIdx.x*128;
    const int n0  = blockIdx.y*128;
    const int c_t = t & 15;
    const int r_t = t >> 4;
    const int arow = t >> 3;
    const int af4  = t & 7;
    const int brow = t >> 5;
    const int bf4  = t & 31;
    float acc[8][8] = {};

    for (int k0 = 0; k0 < K; k0 += 32) {
#pragma unroll
        for (int i = 0; i < 4; i++) {
            int row = i*32 + arow;
            float4 v = *(const float4*)(Amat + (size_t)(m0+row)*lda + k0 + af4*4);
            As[af4*4+0][row] = v.x;
            As[af4*4+1][row] = v.y;
            As[af4*4+2][row] = v.z;
            As[af4*4+3][row] = v.w;
        }
#pragma unroll
        for (int i = 0; i < 4; i++) {
            int row = i*8 + brow;
            *(float4*)&Bs[row][bf4*4] =
                *(const float4*)(Bmat + (size_t)(k0+row)*ldb + n0 + bf4*4);
        }
        __syncthreads();
#pragma unroll
        for (int kk = 0; kk < 32; kk++) {
            float Af[8], Bf[8];
            *(float4*)&Af[0] = *(const float4*)&As[kk][r_t*4];
            *(float4*)&Af[4] = *(const float4*)&As[kk][r_t*4 + 64];
            *(float4*)&Bf[0] = *(const float4*)&Bs[kk][c_t*4];
            *(float4*)&Bf[4] = *(const float4*)&Bs[kk][c_t*4 + 64];
#pragma unroll
            for (int i = 0; i < 8; i++)
#pragma unroll
                for (int j = 0; j < 8; j++)
                    acc[i][j] = fmaf(Af[i], Bf[j], acc[i][j]);
        }
        __syncthreads();
    }
#pragma unroll
    for (int i = 0; i < 8; i++) {
        int row = m0 + (i>>2)*64 + r_t*4 + (i&3);
#pragma unroll
        for (int jg = 0; jg < 2; jg++) {
            int col = n0 + jg*64 + c_t*4;
            float4 o;
            o.x = acc[i][jg*4+0]; o.y = acc[i][jg*4+1];
            o.z = acc[i][jg*4+2]; o.w = acc[i][jg*4+3];
            float g = rowscale[row];
            float4 rr = *(const float4*)(resid + (size_t)row*ldc + col);
            o.x = rr.x + g*o.x; o.y = rr.y + g*o.y;
            o.z = rr.z + g*o.z; o.w = rr.w + g*o.w;
            *(float4*)(Cmat + (size_t)row*ldc + col) = o;
        }
    }
}

// ---------------- transpose + f32->bf16 cast: in [R][C] f32 -> out [C][R] bf16 ----------------
__global__ __launch_bounds__(256) void cvt_transpose(
    const float* __restrict__ in, int R, int C, short* __restrict__ out)
{
    __shared__ short sh[64][68];
    int t  = threadIdx.x;
    int c0 = blockIdx.x * 64, r0 = blockIdx.y * 64;
    int rr = t >> 4, cc = (t & 15) * 4;
#pragma unroll
    for (int p = 0; p < 4; p++) {
        int r = p*16 + rr;
        float4 v = *(const float4*)(in + (size_t)(r0 + r)*C + c0 + cc);
        s16x4 sv = { (short)f2bf(v.x), (short)f2bf(v.y), (short)f2bf(v.z), (short)f2bf(v.w) };
        *(s16x4*)&sh[r][cc] = sv;
    }
    __syncthreads();
#pragma unroll
    for (int p = 0; p < 4; p++) {
        int c = p*16 + rr;   // out row (= in col)
        s16x4 ov = { sh[cc+0][c], sh[cc+1][c], sh[cc+2][c], sh[cc+3][c] };
        *(s16x4*)(out + (size_t)(c0 + c)*R + r0 + cc) = ov;
    }
}

// ---------------- fused rmsnorm2 + bf16 cast: a1[row][k] = bf16(x*rsqrt(mean x^2+eps)*w) ----------------
__global__ __launch_bounds__(256) void ff1prep(
    const float* __restrict__ xatt, const float* __restrict__ n2w,
    short* __restrict__ a1)
{
    int row  = blockIdx.x*4 + (threadIdx.x>>6);
    int lane = threadIdx.x & 63;
    const float4* xr = (const float4*)(xatt + (size_t)row*D_);
    const float4* wr = (const float4*)n2w;
    float4 v[4];
    float s = 0.f;
#pragma unroll
    for (int j = 0; j < 4; j++) {
        v[j] = xr[lane + 64*j];
        s += v[j].x*v[j].x + v[j].y*v[j].y + v[j].z*v[j].z + v[j].w*v[j].w;
    }
#pragma unroll
    for (int off = 32; off > 0; off >>= 1) s += __shfl_xor(s, off);
    float r = rsqrtf(s*(1.f/(float)D_) + EPS_);
#pragma unroll
    for (int j = 0; j < 4; j++) {
        float4 w = wr[lane + 64*j];
        s16x4 o = { (short)f2bf(v[j].x*r*w.x), (short)f2bf(v[j].y*r*w.y),
                    (short)f2bf(v[j].z*r*w.z), (short)f2bf(v[j].w*r*w.w) };
        *(s16x4*)(a1 + (size_t)row*D_ + (lane + 64*j)*4) = o;
    }
}

// ---------------- bf16 MFMA GEMM, B transposed ([N][K]); 128x128 tile, BK=32, 4 waves ----------------
// MODE 0: out bf16 = silu(acc)          (FF1 -> act)
// MODE 1: out f32  = acc + out[in-place] (FF2 -> y, residual already in out)
template<int MODE>
__global__ __launch_bounds__(256) void gemm_bt(
    const short* __restrict__ A,    // [M][K] bf16
    const short* __restrict__ BT,   // [N][K] bf16
    int K, void* __restrict__ Cout, int ldc)
{
    __shared__ short As[2][128*32];
    __shared__ short Bs[2][128*32];

    // bijective XCD swizzle (grid sizes here are multiples of 8)
    int nwg  = gridDim.x * gridDim.y;
    int flat = blockIdx.y * gridDim.x + blockIdx.x;
    int cpx  = nwg >> 3;
    int swz  = (flat & 7) * cpx + (flat >> 3);
    int bx   = swz % gridDim.x;
    int by   = swz / gridDim.x;

    const int t  = threadIdx.x;
    const int l  = t & 63;
    const int w  = t >> 6;
    const int wm = w >> 1, wn = w & 1;
    const size_t m0 = (size_t)bx * 128;
    const size_t n0 = (size_t)by * 128;

    const short* Ab = A  + m0 * (size_t)K;
    const short* Bb = BT + n0 * (size_t)K;

    // fragment read offset (shorts) within a 128x32 tile; chunk col swizzled:
    // LDS slot s of row r holds global k-chunk s ^ ((r>>1)&3); bits1-2 of r are lane bits
    const int rdA = (l & 15)*32 + (((l >> 4) ^ ((l >> 1) & 3)) & 3)*8;

    f32x4 acc[4][4];
    f32x4 zero = {0.f, 0.f, 0.f, 0.f};
#pragma unroll
    for (int i = 0; i < 4; i++)
#pragma unroll
        for (int j = 0; j < 4; j++) acc[i][j] = zero;

    // prologue: stage k-tile 0 into buf 0 (source-side swizzle, linear LDS dest)
#pragma unroll
    for (int j = 0; j < 2; j++) {
        int ch = j*256 + t;
        int r  = ch >> 2;
        int c  = (ch & 3) ^ ((r >> 1) & 3);
        short* dA = &As[0][(j*256 + (t & 192))*8];
        short* dB = &Bs[0][(j*256 + (t & 192))*8];
        gload16(Ab + (size_t)r*K + c*8, dA);
        gload16(Bb + (size_t)r*K + c*8, dB);
    }
    __syncthreads();

    const int nk = K >> 5;
    int cur = 0;
    for (int kt = 0; kt < nk; kt++) {
        if (kt + 1 < nk) {
            int k0 = (kt + 1) << 5;
#pragma unroll
            for (int j = 0; j < 2; j++) {
                int ch = j*256 + t;
                int r  = ch >> 2;
                int c  = (ch & 3) ^ ((r >> 1) & 3);
                short* dA = &As[cur^1][(j*256 + (t & 192))*8];
                short* dB = &Bs[cur^1][(j*256 + (t & 192))*8];
                gload16(Ab + (size_t)r*K + k0 + c*8, dA);
                gload16(Bb + (size_t)r*K + k0 + c*8, dB);
            }
        }
        bf16x8 af[4], bfr[4];
#pragma unroll
        for (int i = 0; i < 4; i++)
            af[i] = *(const bf16x8*)&As[cur][(wm*64 + i*16)*32 + rdA];
#pragma unroll
        for (int j = 0; j < 4; j++)
            bfr[j] = *(const bf16x8*)&Bs[cur][(wn*64 + j*16)*32 + rdA];
#pragma unroll
        for (int i = 0; i < 4; i++)
#pragma unroll
            for (int j = 0; j < 4; j++)
                acc[i][j] = __builtin_amdgcn_mfma_f32_16x16x32_bf16(
                    af[i], bfr[j], acc[i][j], 0, 0, 0);
        __syncthreads();   // drains vmcnt (next-tile stage) + all waves done reading cur
        cur ^= 1;
    }

    // epilogue: C/D layout col=l&15, row=(l>>4)*4+v
#pragma unroll
    for (int i = 0; i < 4; i++) {
        size_t row_base = m0 + wm*64 + i*16 + (l >> 4)*4;
#pragma unroll
        for (int j = 0; j < 4; j++) {
            size_t col = n0 + wn*64 + j*16 + (l & 15);
#pragma unroll
            for (int v = 0; v < 4; v++) {
                size_t row = row_base + v;
                float val = acc[i][j][v];
                if (MODE == 0) {
                    ((short*)Cout)[row * ldc + col] = (short)f2bf(siluf_(val));
                } else {
                    float* p = (float*)Cout + row * ldc + col;
                    *p = val + *p;
                }
            }
        }
    }
}

extern "C" void kernel_launch(void* const* d_in, const int* in_sizes, int n_in,
                              void* d_out, int out_size, void* d_ws, size_t ws_size,
                              hipStream_t stream)
{
    const float* x    = (const float*)d_in[0];
    const float* n1w  = (const float*)d_in[1];
    const float* n2w  = (const float*)d_in[2];
    const float* araw = (const float*)d_in[3];
    const float* bw   = (const float*)d_in[4];
    const float* cw   = (const float*)d_in[5];
    const float* Wq   = (const float*)d_in[6];
    const float* Wk   = (const float*)d_in[7];
    const float* Wv   = (const float*)d_in[8];
    const float* Wo   = (const float*)d_in[9];
    const float* Wg   = (const float*)d_in[10];
    const float* gb   = (const float*)d_in[11];
    const float* ffw1 = (const float*)d_in[12];
    const float* ffw2 = (const float*)d_in[13];
    float* out = (float*)d_out;

    float* ws    = (float*)d_ws;
    float* rms1  = ws;                                   // N_
    float* gate  = rms1  + N_;                           // N_
    float* cpart = gate  + N_;                           // B_*NCHUNK_*D_
    float* cin   = cpart + (size_t)B_*NCHUNK_*D_;        // B_*NCHUNK_*D_
    float* qb    = cin   + (size_t)B_*NCHUNK_*D_;        // N_*A_
    float* kb    = qb    + (size_t)N_*A_;
    float* vb    = kb    + (size_t)N_*A_;
    float* attnb = vb    + (size_t)N_*A_;
    float* x_ssm = attnb + (size_t)N_*A_;                // N_*D_
    short* a1    = (short*)(x_ssm + (size_t)N_*D_);      // N_*D_ bf16
    short* act   = a1    + (size_t)N_*D_;                // N_*FF_ bf16
    short* w1t   = act   + (size_t)N_*FF_;               // FF_*D_ bf16 (ff_w1^T)
    short* w2t   = w1t   + (size_t)FF_*D_;               // D_*FF_ bf16 (ff_w2^T)

    // weight convert+transpose (independent; runs up front)
    cvt_transpose<<<dim3(FF_/64, D_/64), 256, 0, stream>>>(ffw1, D_, FF_, w1t);
    cvt_transpose<<<dim3(D_/64, FF_/64), 256, 0, stream>>>(ffw2, FF_, D_, w2t);

    // 1. rms of x
    rms_kernel<<<N_/4, 256, 0, stream>>>(x, rms1);
    // 2-4. chunked SSM scan -> x_ssm = x + h*c_w
    scan1_kernel<<<dim3(D_/64, NCHUNK_, B_), 64, 0, stream>>>(x, rms1, n1w, bw, araw, cpart);
    scan2_kernel<<<(B_*D_)/256, 256, 0, stream>>>(araw, cpart, cin);
    scan3_kernel<<<dim3(D_/64, NCHUNK_, B_), 64, 0, stream>>>(x, rms1, n1w, bw, cw, araw, cin, x_ssm);
    // 5. q,k,v projections (f32)
    gemm_qkv<<<dim3(N_/128, 3), 256, 0, stream>>>(x_ssm, Wq, Wk, Wv, qb, kb, vb);
    // 6. gate
    gate_kernel<<<N_/4, 256, 0, stream>>>(x_ssm, Wg, gb, gate);
    // 7. sliding-window attention
    attn_kernel<<<dim3(L_/64, B_), 256, 0, stream>>>(qb, kb, vb, attnb);
    // 8. x_att = x_ssm + gate * (attn @ Wo)  (into d_out)
    gemm128<2><<<dim3(N_/128, D_/128), 256, 0, stream>>>(attnb, A_, A_, Wo, D_, out, D_,
                                                         gate, (const float*)0, x_ssm);
    // 9. a1 = bf16(rmsnorm(x_att) * n2w)
    ff1prep<<<N_/4, 256, 0, stream>>>(out, n2w, a1);
    // 10. act = bf16(silu(a1 @ w1))   [MFMA]
    gemm_bt<0><<<dim3(N_/128, FF_/128), 256, 0, stream>>>(a1, w1t, D_, (void*)act, FF_);
    // 11. y = x_att + act @ w2        [MFMA, in-place residual on d_out]
    gemm_bt<1><<<dim3(N_/128, D_/128), 256, 0, stream>>>(act, w2t, FF_, (void*)out, D_);
}

// Round 3
// 478.178 us; speedup vs baseline: 4.0710x; 1.3541x over previous
//
#include <hip/hip_runtime.h>
#include <math.h>

#define B_ 4
#define L_ 4096
#define D_ 1024
#define A_ 64
#define FF_ 2048
#define N_ (B_*L_)
#define EPS_ 1e-6f
#define CHUNK_ 128
#define NCHUNK_ (L_/CHUNK_)

typedef __attribute__((ext_vector_type(8))) short bf16x8;
typedef __attribute__((ext_vector_type(4))) short s16x4;
typedef __attribute__((ext_vector_type(4))) float f32x4;

static __device__ __forceinline__ float sigmoidf_(float x) { return 1.f/(1.f+expf(-x)); }
static __device__ __forceinline__ float siluf_(float x)    { return x/(1.f+expf(-x)); }

static __device__ __forceinline__ unsigned short f2bf(float f) {
    unsigned u = __float_as_uint(f);
    u += 0x7fffu + ((u >> 16) & 1u);        // RNE
    return (unsigned short)(u >> 16);
}

// async global->LDS, 16B per lane; lds ptr wave-uniform (HW adds lane*16)
static __device__ __forceinline__ void gload16(const short* g, short* l) {
    __builtin_amdgcn_global_load_lds(
        (const __attribute__((address_space(1))) void*)g,
        (__attribute__((address_space(3))) void*)l, 16, 0, 0);
}

// ---------------- rms (one wave per row) ----------------
__global__ __launch_bounds__(256) void rms_kernel(const float* __restrict__ x,
                                                  float* __restrict__ rms)
{
    int row  = blockIdx.x*4 + (threadIdx.x>>6);
    int lane = threadIdx.x & 63;
    const float4* xr = (const float4*)(x + (size_t)row*D_);
    float s = 0.f;
#pragma unroll
    for (int j = 0; j < 4; j++) {
        float4 v = xr[lane + 64*j];
        s += v.x*v.x + v.y*v.y + v.z*v.z + v.w*v.w;
    }
#pragma unroll
    for (int off = 32; off > 0; off >>= 1) s += __shfl_xor(s, off);
    if (lane == 0) rms[row] = rsqrtf(s*(1.f/(float)D_) + EPS_);
}

// ---------------- SSM scan phase 1 ----------------
__global__ __launch_bounds__(64) void scan1_kernel(
    const float* __restrict__ x, const float* __restrict__ rms1,
    const float* __restrict__ n1w, const float* __restrict__ bw,
    const float* __restrict__ araw, float* __restrict__ cpart)
{
    int d = blockIdx.x*64 + threadIdx.x;
    int c = blockIdx.y;
    int b = blockIdx.z;
    float a = sigmoidf_(araw[d]);
    float w = n1w[d]*bw[d];
    float h = 0.f;
    size_t base = ((size_t)b*L_ + (size_t)c*CHUNK_)*D_ + d;
    const float* rp = rms1 + b*L_ + c*CHUNK_;
#pragma unroll 8
    for (int t = 0; t < CHUNK_; t++) {
        float u = x[base + (size_t)t*D_] * rp[t] * w;
        h = a*h + u;
    }
    cpart[((size_t)b*NCHUNK_ + c)*D_ + d] = h;
}

// ---------------- SSM scan phase 2 ----------------
__global__ __launch_bounds__(256) void scan2_kernel(
    const float* __restrict__ araw, const float* __restrict__ cpart,
    float* __restrict__ cin)
{
    int idx = blockIdx.x*256 + threadIdx.x;
    int b = idx >> 10;
    int d = idx & (D_-1);
    float a = sigmoidf_(araw[d]);
    float aT = a;
#pragma unroll
    for (int i = 0; i < 7; i++) aT *= aT;     // a^128
    float cy = 0.f;
    for (int c = 0; c < NCHUNK_; c++) {
        size_t o = ((size_t)b*NCHUNK_ + c)*D_ + d;
        cin[o] = cy;
        cy = aT*cy + cpart[o];
    }
}

// ---------------- SSM scan phase 3: writes x_ssm f32 + bf16 ----------------
__global__ __launch_bounds__(64) void scan3_kernel(
    const float* __restrict__ x, const float* __restrict__ rms1,
    const float* __restrict__ n1w, const float* __restrict__ bw,
    const float* __restrict__ cw, const float* __restrict__ araw,
    const float* __restrict__ cin, float* __restrict__ x_ssm,
    short* __restrict__ xsb)
{
    int d = blockIdx.x*64 + threadIdx.x;
    int c = blockIdx.y;
    int b = blockIdx.z;
    float a = sigmoidf_(araw[d]);
    float w = n1w[d]*bw[d];
    float cwd = cw[d];
    float h = cin[((size_t)b*NCHUNK_ + c)*D_ + d];
    size_t base = ((size_t)b*L_ + (size_t)c*CHUNK_)*D_ + d;
    const float* rp = rms1 + b*L_ + c*CHUNK_;
#pragma unroll 8
    for (int t = 0; t < CHUNK_; t++) {
        size_t p = base + (size_t)t*D_;
        float xv = x[p];
        h = a*h + xv * rp[t] * w;
        float o = xv + h*cwd;
        x_ssm[p] = o;
        xsb[p] = (short)f2bf(o);
    }
}

// ---------------- gate ----------------
__global__ __launch_bounds__(256) void gate_kernel(
    const float* __restrict__ xs, const float* __restrict__ Wg,
    const float* __restrict__ gb, float* __restrict__ gate)
{
    int row  = blockIdx.x*4 + (threadIdx.x>>6);
    int lane = threadIdx.x & 63;
    const float4* xr = (const float4*)(xs + (size_t)row*D_);
    const float4* wr = (const float4*)Wg;
    float s = 0.f;
#pragma unroll
    for (int j = 0; j < 4; j++) {
        float4 xv = xr[lane + 64*j];
        float4 wv = wr[lane + 64*j];
        s += xv.x*wv.x + xv.y*wv.y + xv.z*wv.z + xv.w*wv.w;
    }
#pragma unroll
    for (int off = 32; off > 0; off >>= 1) s += __shfl_xor(s, off);
    if (lane == 0) gate[row] = sigmoidf_(s + gb[0]);
}

// ---------------- sliding-window attention (f32 in, bf16 out) ----------------
__global__ __launch_bounds__(256) void attn_kernel(
    const float* __restrict__ qm, const float* __restrict__ km,
    const float* __restrict__ vm, short* __restrict__ om)
{
    __shared__ float KV[128][68];
    int b  = blockIdx.y;
    int l0 = blockIdx.x*64;
    int t  = threadIdx.x;
    int r  = t >> 2;
    int qq = t & 3;

#pragma unroll
    for (int i = 0; i < 8; i++) {
        int lin = i*256 + t;
        int row = lin >> 4;
        int f4  = lin & 15;
        int gl  = l0 - 64 + row;
        float4 val = make_float4(0.f,0.f,0.f,0.f);
        if (gl >= 0) val = *(const float4*)(km + ((size_t)b*L_ + gl)*A_ + f4*4);
        *(float4*)&KV[row][f4*4] = val;
    }
    float4 qreg[16];
    {
        const float* qrow = qm + ((size_t)b*L_ + l0 + r)*A_;
#pragma unroll
        for (int j = 0; j < 16; j++) qreg[j] = *(const float4*)(qrow + j*4);
    }
    __syncthreads();

    float s[16];
#pragma unroll
    for (int wi = 0; wi < 16; wi++) {
        int w  = qq*16 + wi;
        int tr = r + w + 1;
        float dot = 0.f;
#pragma unroll
        for (int j = 0; j < 16; j++) {
            float4 kv = *(const float4*)&KV[tr][j*4];
            dot += qreg[j].x*kv.x + qreg[j].y*kv.y + qreg[j].z*kv.z + qreg[j].w*kv.w;
        }
        s[wi] = (l0 + r - 63 + w >= 0) ? dot*0.125f : -INFINITY;
    }
    float mx = s[0];
#pragma unroll
    for (int wi = 1; wi < 16; wi++) mx = fmaxf(mx, s[wi]);
    mx = fmaxf(mx, __shfl_xor(mx, 1));
    mx = fmaxf(mx, __shfl_xor(mx, 2));
    float sum = 0.f;
#pragma unroll
    for (int wi = 0; wi < 16; wi++) { s[wi] = expf(s[wi] - mx); sum += s[wi]; }
    sum += __shfl_xor(sum, 1);
    sum += __shfl_xor(sum, 2);
    float inv = 1.f/sum;
#pragma unroll
    for (int wi = 0; wi < 16; wi++) s[wi] *= inv;

    __syncthreads();
#pragma unroll
    for (int i = 0; i < 8; i++) {
        int lin = i*256 + t;
        int row = lin >> 4;
        int f4  = lin & 15;
        int gl  = l0 - 64 + row;
        float4 val = make_float4(0.f,0.f,0.f,0.f);
        if (gl >= 0) val = *(const float4*)(vm + ((size_t)b*L_ + gl)*A_ + f4*4);
        *(float4*)&KV[row][f4*4] = val;
    }
    __syncthreads();

    float4 acc[4];
#pragma unroll
    for (int ss = 0; ss < 4; ss++) acc[ss] = make_float4(0.f,0.f,0.f,0.f);
#pragma unroll
    for (int w = 0; w < 64; w++) {
        float pv = __shfl(s[w & 15], (t & 60) + (w >> 4));
        int tr = r + w + 1;
#pragma unroll
        for (int ss = 0; ss < 4; ss++) {
            float4 vv = *(const float4*)&KV[tr][qq*16 + ss*4];
            acc[ss].x += pv*vv.x; acc[ss].y += pv*vv.y;
            acc[ss].z += pv*vv.z; acc[ss].w += pv*vv.w;
        }
    }
    short* orow = om + ((size_t)b*L_ + l0 + r)*A_ + qq*16;
#pragma unroll
    for (int ss = 0; ss < 4; ss++) {
        s16x4 ov = { (short)f2bf(acc[ss].x), (short)f2bf(acc[ss].y),
                     (short)f2bf(acc[ss].z), (short)f2bf(acc[ss].w) };
        *(s16x4*)(orow + ss*4) = ov;
    }
}

// ---------------- transpose + f32->bf16 cast: in [R][C] f32 -> out [C][R] bf16 ----------------
__global__ __launch_bounds__(256) void cvt_transpose(
    const float* __restrict__ in, int R, int C, short* __restrict__ out)
{
    __shared__ short sh[64][68];
    int t  = threadIdx.x;
    int c0 = blockIdx.x * 64, r0 = blockIdx.y * 64;
    int rr = t >> 4, cc = (t & 15) * 4;
#pragma unroll
    for (int p = 0; p < 4; p++) {
        int r = p*16 + rr;
        float4 v = *(const float4*)(in + (size_t)(r0 + r)*C + c0 + cc);
        s16x4 sv = { (short)f2bf(v.x), (short)f2bf(v.y), (short)f2bf(v.z), (short)f2bf(v.w) };
        *(s16x4*)&sh[r][cc] = sv;
    }
    __syncthreads();
#pragma unroll
    for (int p = 0; p < 4; p++) {
        int c = p*16 + rr;
        s16x4 ov = { sh[cc+0][c], sh[cc+1][c], sh[cc+2][c], sh[cc+3][c] };
        *(s16x4*)(out + (size_t)(c0 + c)*R + r0 + cc) = ov;
    }
}

// ---------------- fused rmsnorm2 + bf16 cast ----------------
__global__ __launch_bounds__(256) void ff1prep(
    const float* __restrict__ xatt, const float* __restrict__ n2w,
    short* __restrict__ a1)
{
    int row  = blockIdx.x*4 + (threadIdx.x>>6);
    int lane = threadIdx.x & 63;
    const float4* xr = (const float4*)(xatt + (size_t)row*D_);
    const float4* wr = (const float4*)n2w;
    float4 v[4];
    float s = 0.f;
#pragma unroll
    for (int j = 0; j < 4; j++) {
        v[j] = xr[lane + 64*j];
        s += v[j].x*v[j].x + v[j].y*v[j].y + v[j].z*v[j].z + v[j].w*v[j].w;
    }
#pragma unroll
    for (int off = 32; off > 0; off >>= 1) s += __shfl_xor(s, off);
    float r = rsqrtf(s*(1.f/(float)D_) + EPS_);
#pragma unroll
    for (int j = 0; j < 4; j++) {
        float4 w = wr[lane + 64*j];
        s16x4 o = { (short)f2bf(v[j].x*r*w.x), (short)f2bf(v[j].y*r*w.y),
                    (short)f2bf(v[j].z*r*w.z), (short)f2bf(v[j].w*r*w.w) };
        *(s16x4*)(a1 + (size_t)row*D_ + (lane + 64*j)*4) = o;
    }
}

// ---------------- QKV: [N_][1024]bf16 @ [192][1024]bf16^T -> q,k,v f32 ----------------
__global__ __launch_bounds__(256) void qkv_mfma(
    const short* __restrict__ A, const short* __restrict__ BT,
    float* __restrict__ qo, float* __restrict__ ko, float* __restrict__ vo)
{
    __shared__ short As2[2][64*32];
    __shared__ short Bs2[2][192*32];
    const int t = threadIdx.x, l = t & 63, w = t >> 6;
    const size_t m0 = (size_t)blockIdx.x*64;
    const short* Ab = A + m0*D_;

    const int ar = w*16 + (l&15);
    const int offA = ar*32 + (((l>>4) ^ ((ar>>1)&3)) & 3)*8;
    int offB[12];
#pragma unroll
    for (int j = 0; j < 12; j++) {
        int br = j*16 + (l&15);
        offB[j] = br*32 + (((l>>4) ^ ((br>>1)&3)) & 3)*8;
    }

#define QSTG(bi, k0) { \
        { int r = t>>2; int lc = (t&3) ^ ((r>>1)&3); \
          gload16(Ab + (size_t)r*D_ + (k0) + lc*8, &As2[bi][(w*64)*8]); } \
        _Pragma("unroll") \
        for (int i_ = 0; i_ < 3; i_++) { \
            int s_ = i_*256 + t; int r = s_>>2; int lc = (s_&3) ^ ((r>>1)&3); \
            gload16(BT + (size_t)r*D_ + (k0) + lc*8, &Bs2[bi][(i_*256 + w*64)*8]); } }

    f32x4 acc[12];
    f32x4 zero = {0.f,0.f,0.f,0.f};
#pragma unroll
    for (int j = 0; j < 12; j++) acc[j] = zero;

    QSTG(0, 0);
    __syncthreads();
    int cur = 0;
    for (int kt = 0; kt < 32; kt++) {
        if (kt + 1 < 32) QSTG(cur^1, (kt+1)*32);
        bf16x8 af = *(const bf16x8*)&As2[cur][offA];
#pragma unroll
        for (int j = 0; j < 12; j++) {
            bf16x8 bfv = *(const bf16x8*)&Bs2[cur][offB[j]];
            acc[j] = __builtin_amdgcn_mfma_f32_16x16x32_bf16(af, bfv, acc[j], 0, 0, 0);
        }
        __syncthreads();
        cur ^= 1;
    }
#pragma unroll
    for (int j = 0; j < 12; j++) {
        int col = j*16 + (l&15);
        int mat = col >> 6, c = col & 63;
        float* dst = (mat == 0) ? qo : (mat == 1) ? ko : vo;
#pragma unroll
        for (int v = 0; v < 4; v++) {
            size_t row = m0 + w*16 + (l>>4)*4 + v;
            dst[row*A_ + c] = acc[j][v];
        }
    }
#undef QSTG
}

// ---------------- WO: out = resid + gate*(attn_bf16 @ wot^T), K=64 ----------------
__global__ __launch_bounds__(256) void gemm_wo(
    const short* __restrict__ A,   // attnb [N_][64]
    const short* __restrict__ BT,  // wot [1024][64]
    const float* __restrict__ gate, const float* __restrict__ resid,
    float* __restrict__ Cout)
{
    __shared__ short As3[128*64];
    __shared__ short Bs3[128*64];
    const int t = threadIdx.x, l = t & 63, w = t >> 6;
    const int wm = w >> 1, wn = w & 1;
    const size_t m0 = (size_t)blockIdx.x*128, n0 = (size_t)blockIdx.y*128;

#pragma unroll
    for (int i = 0; i < 4; i++) {
        int s = i*256 + t;
        int r = s >> 3, lc = (s&7) ^ (r&7);
        gload16(A  + (m0 + r)*64 + lc*8, &As3[(i*256 + w*64)*8]);
        gload16(BT + (n0 + r)*64 + lc*8, &Bs3[(i*256 + w*64)*8]);
    }
    __syncthreads();

    f32x4 acc[4][4];
    f32x4 zero = {0.f,0.f,0.f,0.f};
#pragma unroll
    for (int i = 0; i < 4; i++)
#pragma unroll
        for (int j = 0; j < 4; j++) acc[i][j] = zero;

#pragma unroll
    for (int kk = 0; kk < 2; kk++) {
        bf16x8 af[4], bfv[4];
#pragma unroll
        for (int i = 0; i < 4; i++) {
            int ar = wm*64 + i*16 + (l&15);
            int pch = (kk*4 + (l>>4)) ^ (ar&7);
            af[i] = *(const bf16x8*)&As3[ar*64 + pch*8];
        }
#pragma unroll
        for (int j = 0; j < 4; j++) {
            int br = wn*64 + j*16 + (l&15);
            int pch = (kk*4 + (l>>4)) ^ (br&7);
            bfv[j] = *(const bf16x8*)&Bs3[br*64 + pch*8];
        }
#pragma unroll
        for (int i = 0; i < 4; i++)
#pragma unroll
            for (int j = 0; j < 4; j++)
                acc[i][j] = __builtin_amdgcn_mfma_f32_16x16x32_bf16(af[i], bfv[j], acc[i][j], 0, 0, 0);
    }

#pragma unroll
    for (int i = 0; i < 4; i++) {
#pragma unroll
        for (int v = 0; v < 4; v++) {
            size_t row = m0 + wm*64 + i*16 + (l>>4)*4 + v;
            float g = gate[row];
#pragma unroll
            for (int j = 0; j < 4; j++) {
                size_t col = n0 + wn*64 + j*16 + (l&15);
                Cout[row*D_ + col] = resid[row*D_ + col] + g*acc[i][j][v];
            }
        }
    }
}

// ---------------- 256x256 bf16 MFMA GEMM, BK=32, 8 waves, 4-slot LDS ring, counted vmcnt ----------------
// MODE 0: Cout bf16 = silu(acc); MODE 1: Cout f32 += acc (in-place residual)
template<int K, int MODE>
__global__ __launch_bounds__(512, 2) void gemm256(
    const short* __restrict__ A,   // [M][K]
    const short* __restrict__ BT,  // [N][K]
    void* __restrict__ Cout, int ldc)
{
    __shared__ short As[4][256*32];   // 64 KiB
    __shared__ short Bs[4][256*32];   // 64 KiB

    // XCD swizzle: consecutive work ids share the A row-panel; chunk per XCD
    const int gy = gridDim.y;
    const int nwg = gridDim.x * gy;
    const int o = blockIdx.y * gridDim.x + blockIdx.x;   // HW dispatch order (x fastest)
    const int q = nwg >> 3;
    const int swz = (o & 7)*q + (o >> 3);
    const int bx = swz / gy, by = swz % gy;

    const int t = threadIdx.x;
    const int l = t & 63;
    const int w = t >> 6;          // 0..7
    const int wm = w >> 2;         // 0..1  (row half)
    const int wn = w & 3;          // 0..3  (col quarter)
    const size_t m0 = (size_t)bx * 256;
    const size_t n0 = (size_t)by * 256;
    const short* Ab = A  + m0 * (size_t)K;
    const short* Bb = BT + n0 * (size_t)K;
    const int s0 = w*64 + l;       // stage slot for instr 0

    // fragment read offsets (shorts): row*32 + physchunk*8, chunk swizz = ^((row>>1)&3)
    int offA[8], offB[4];
#pragma unroll
    for (int i = 0; i < 8; i++) {
        int ar = wm*128 + i*16 + (l&15);
        offA[i] = ar*32 + (((l>>4) ^ ((ar>>1)&3)) & 3)*8;
    }
#pragma unroll
    for (int j = 0; j < 4; j++) {
        int br = wn*64 + j*16 + (l&15);
        offB[j] = br*32 + (((l>>4) ^ ((br>>1)&3)) & 3)*8;
    }

#define STAGE_A(bi, k0) { _Pragma("unroll") \
    for (int i_ = 0; i_ < 2; i_++) { \
        int s_ = i_*512 + s0; int r_ = s_>>2; int lc_ = (s_&3) ^ ((r_>>1)&3); \
        gload16(Ab + (size_t)r_*K + (k0) + lc_*8, &As[bi][(i_*512 + w*64)*8]); } }
#define STAGE_B(bi, k0) { _Pragma("unroll") \
    for (int i_ = 0; i_ < 2; i_++) { \
        int s_ = i_*512 + s0; int r_ = s_>>2; int lc_ = (s_&3) ^ ((r_>>1)&3); \
        gload16(Bb + (size_t)r_*K + (k0) + lc_*8, &Bs[bi][(i_*512 + w*64)*8]); } }

    f32x4 acc[8][4];
    f32x4 zero = {0.f,0.f,0.f,0.f};
#pragma unroll
    for (int i = 0; i < 8; i++)
#pragma unroll
        for (int j = 0; j < 4; j++) acc[i][j] = zero;

    // prologue: tiles 0,1 staged; wait tile 0 landed (tile 1 stays in flight)
    STAGE_A(0, 0);  STAGE_B(0, 0);
    STAGE_A(1, 32); STAGE_B(1, 32);
    asm volatile("s_waitcnt vmcnt(4)" ::: "memory");
    __builtin_amdgcn_s_barrier();

    const int nk = K >> 5;
#pragma unroll 1
    for (int kt = 0; kt < nk; kt++) {
        const short* a_ = &As[kt & 3][0];
        const short* b_ = &Bs[kt & 3][0];
        const int prefetch = (kt + 2 < nk);
        const int pb = (kt + 2) & 3;
        const int pk = (kt + 2) << 5;

        // phase 0: B frags + A frags 0-3, stage A of tile kt+2, 16 MFMA
        bf16x8 bfv[4], af[4];
#pragma unroll
        for (int j = 0; j < 4; j++) bfv[j] = *(const bf16x8*)(b_ + offB[j]);
#pragma unroll
        for (int i = 0; i < 4; i++) af[i] = *(const bf16x8*)(a_ + offA[i]);
        if (prefetch) STAGE_A(pb, pk);
        __builtin_amdgcn_s_setprio(1);
#pragma unroll
        for (int i = 0; i < 4; i++)
#pragma unroll
            for (int j = 0; j < 4; j++)
                acc[i][j] = __builtin_amdgcn_mfma_f32_16x16x32_bf16(af[i], bfv[j], acc[i][j], 0, 0, 0);
        __builtin_amdgcn_s_setprio(0);

        // phase 1: A frags 4-7 (B reused), stage B of tile kt+2, 16 MFMA
#pragma unroll
        for (int i = 0; i < 4; i++) af[i] = *(const bf16x8*)(a_ + offA[4+i]);
        if (prefetch) STAGE_B(pb, pk);
        __builtin_amdgcn_s_setprio(1);
#pragma unroll
        for (int i = 0; i < 4; i++)
#pragma unroll
            for (int j = 0; j < 4; j++)
                acc[4+i][j] = __builtin_amdgcn_mfma_f32_16x16x32_bf16(af[i], bfv[j], acc[4+i][j], 0, 0, 0);
        __builtin_amdgcn_s_setprio(0);

        // tile boundary: tile kt+1's 4 loads (older than kt+2's 4) must be done
        if (prefetch) { asm volatile("s_waitcnt vmcnt(4)" ::: "memory"); }
        else          { asm volatile("s_waitcnt vmcnt(0)" ::: "memory"); }
        __builtin_amdgcn_s_barrier();
    }

    // epilogue: C/D layout col=l&15, row=(l>>4)*4+v
#pragma unroll
    for (int i = 0; i < 8; i++) {
        size_t row_base = m0 + wm*128 + i*16 + (l >> 4)*4;
#pragma unroll
        for (int j = 0; j < 4; j++) {
            size_t col = n0 + wn*64 + j*16 + (l & 15);
#pragma unroll
            for (int v = 0; v < 4; v++) {
                size_t row = row_base + v;
                float val = acc[i][j][v];
                if (MODE == 0) {
                    ((short*)Cout)[row * ldc + col] = (short)f2bf(siluf_(val));
                } else {
                    float* p = (float*)Cout + row * ldc + col;
                    *p = val + *p;
                }
            }
        }
    }
#undef STAGE_A
#undef STAGE_B
}

extern "C" void kernel_launch(void* const* d_in, const int* in_sizes, int n_in,
                              void* d_out, int out_size, void* d_ws, size_t ws_size,
                              hipStream_t stream)
{
    const float* x    = (const float*)d_in[0];
    const float* n1w  = (const float*)d_in[1];
    const float* n2w  = (const float*)d_in[2];
    const float* araw = (const float*)d_in[3];
    const float* bw   = (const float*)d_in[4];
    const float* cw   = (const float*)d_in[5];
    const float* Wq   = (const float*)d_in[6];
    const float* Wk   = (const float*)d_in[7];
    const float* Wv   = (const float*)d_in[8];
    const float* Wo   = (const float*)d_in[9];
    const float* Wg   = (const float*)d_in[10];
    const float* gb   = (const float*)d_in[11];
    const float* ffw1 = (const float*)d_in[12];
    const float* ffw2 = (const float*)d_in[13];
    float* out = (float*)d_out;

    float* ws    = (float*)d_ws;
    float* rms1  = ws;                                   // N_
    float* gate  = rms1  + N_;                           // N_
    float* cpart = gate  + N_;                           // B_*NCHUNK_*D_
    float* cin   = cpart + (size_t)B_*NCHUNK_*D_;        // B_*NCHUNK_*D_
    float* qb    = cin   + (size_t)B_*NCHUNK_*D_;        // N_*A_
    float* kb    = qb    + (size_t)N_*A_;
    float* vb    = kb    + (size_t)N_*A_;
    float* x_ssm = vb    + (size_t)N_*A_;                // N_*D_ f32
    short* xsb   = (short*)(x_ssm + (size_t)N_*D_);      // N_*D_ bf16
    short* attnb = xsb   + (size_t)N_*D_;                // N_*A_ bf16
    short* a1    = attnb + (size_t)N_*A_;                // N_*D_ bf16
    short* act   = a1    + (size_t)N_*D_;                // N_*FF_ bf16
    short* w1t   = act   + (size_t)N_*FF_;               // FF_*D_ bf16
    short* w2t   = w1t   + (size_t)FF_*D_;               // D_*FF_ bf16
    short* wqkvT = w2t   + (size_t)D_*FF_;               // 192*D_ bf16
    short* wot   = wqkvT + (size_t)192*D_;               // D_*A_ bf16

    // weight convert+transpose
    cvt_transpose<<<dim3(FF_/64, D_/64), 256, 0, stream>>>(ffw1, D_, FF_, w1t);
    cvt_transpose<<<dim3(D_/64, FF_/64), 256, 0, stream>>>(ffw2, FF_, D_, w2t);
    cvt_transpose<<<dim3(1, D_/64), 256, 0, stream>>>(Wq, D_, A_, wqkvT);
    cvt_transpose<<<dim3(1, D_/64), 256, 0, stream>>>(Wk, D_, A_, wqkvT + (size_t)A_*D_);
    cvt_transpose<<<dim3(1, D_/64), 256, 0, stream>>>(Wv, D_, A_, wqkvT + (size_t)2*A_*D_);
    cvt_transpose<<<dim3(D_/64, 1), 256, 0, stream>>>(Wo, A_, D_, wot);

    // 1. rms of x
    rms_kernel<<<N_/4, 256, 0, stream>>>(x, rms1);
    // 2-4. chunked SSM scan -> x_ssm (f32 + bf16)
    scan1_kernel<<<dim3(D_/64, NCHUNK_, B_), 64, 0, stream>>>(x, rms1, n1w, bw, araw, cpart);
    scan2_kernel<<<(B_*D_)/256, 256, 0, stream>>>(araw, cpart, cin);
    scan3_kernel<<<dim3(D_/64, NCHUNK_, B_), 64, 0, stream>>>(x, rms1, n1w, bw, cw, araw, cin, x_ssm, xsb);
    // 5. q,k,v projections [MFMA]
    qkv_mfma<<<N_/64, 256, 0, stream>>>(xsb, wqkvT, qb, kb, vb);
    // 6. gate
    gate_kernel<<<N_/4, 256, 0, stream>>>(x_ssm, Wg, gb, gate);
    // 7. sliding-window attention (bf16 out)
    attn_kernel<<<dim3(L_/64, B_), 256, 0, stream>>>(qb, kb, vb, attnb);
    // 8. x_att = x_ssm + gate * (attn @ Wo) [MFMA] -> d_out
    gemm_wo<<<dim3(N_/128, D_/128), 256, 0, stream>>>(attnb, wot, gate, x_ssm, out);
    // 9. a1 = bf16(rmsnorm(x_att) * n2w)
    ff1prep<<<N_/4, 256, 0, stream>>>(out, n2w, a1);
    // 10. act = bf16(silu(a1 @ w1)) [MFMA 256^2 pipelined]
    gemm256<D_, 0><<<dim3(N_/256, FF_/256), 512, 0, stream>>>(a1, w1t, (void*)act, FF_);
    // 11. y = x_att + act @ w2 [MFMA 256^2 pipelined, in-place]
    gemm256<FF_, 1><<<dim3(N_/256, D_/256), 512, 0, stream>>>(act, w2t, (void*)out, D_);
}